// Round 2
// baseline (670.064 us; speedup 1.0000x reference)
//
#include <hip/hip_runtime.h>
#include <hip/hip_bf16.h>

// DeepseekV4 shared expert: int8 dynamic-quant SwiGLU MLP.
// T=8192, H=4096, I=2048.
// Pipeline: wconv x3 -> quant_x -> gemm1(gate+up fused, silu, clip, bf16)
//           -> quant_inter -> gemm2 -> out fp32.
//
// GEMMs: 8-phase-style schedule (per-phase barrier-sandwiched MFMA clusters,
// stage-issue + ds_read before the barrier, counted vmcnt once per K-tile,
// never drained to 0 in steady state), XOR bank-swizzled LDS, setprio around
// MFMA clusters. gemm1: 3-buffer lead-2 (vmcnt(6)); gemm2: 4-buffer lead-3
// (vmcnt(8)).

typedef __attribute__((ext_vector_type(4))) int i32x4;

__device__ __forceinline__ void async16(void* lds, const void* g) {
  __builtin_amdgcn_global_load_lds(
      (const __attribute__((address_space(1))) void*)g,
      (__attribute__((address_space(3))) void*)lds, 16, 0, 0);
}

__device__ __forceinline__ i32x4 mfma_i8(i32x4 a, i32x4 b, i32x4 c) {
  return __builtin_amdgcn_mfma_i32_16x16x64_i8(a, b, c, 0, 0, 0);
}

// fp32 -> bf16 round-to-nearest-even, back to fp32
__device__ __forceinline__ float bf16_rne_f(float f) {
  unsigned u = __float_as_uint(f);
  u += 0x7fffu + ((u >> 16) & 1u);
  return __uint_as_float(u & 0xffff0000u);
}

__device__ __forceinline__ unsigned short bf16_bits(float f) {
  unsigned u = __float_as_uint(f);
  u += 0x7fffu + ((u >> 16) & 1u);
  return (unsigned short)(u >> 16);
}

__device__ __forceinline__ float bf16_to_f(unsigned short h) {
  return __uint_as_float(((unsigned)h) << 16);
}

#define BARRIER __builtin_amdgcn_s_barrier()
#define LGKM0 asm volatile("s_waitcnt lgkmcnt(0)" ::: "memory")
#define WAIT_VM8 asm volatile("s_waitcnt vmcnt(8)" ::: "memory")
#define WAIT_VM6 asm volatile("s_waitcnt vmcnt(6)" ::: "memory")
#define WAIT_VM4 asm volatile("s_waitcnt vmcnt(4)" ::: "memory")
#define WAIT_VM0 asm volatile("s_waitcnt vmcnt(0)" ::: "memory")

// ---------------- weight fp32 (int8-valued) -> int8 ----------------
__global__ void wconv_kernel(const float* __restrict__ w,
                             signed char* __restrict__ wq, int n) {
  int i = (blockIdx.x * 256 + threadIdx.x) * 4;
  if (i >= n) return;
  float4 f = *(const float4*)(w + i);
  signed char c[4] __attribute__((aligned(4)));
  c[0] = (signed char)(int)rintf(f.x);
  c[1] = (signed char)(int)rintf(f.y);
  c[2] = (signed char)(int)rintf(f.z);
  c[3] = (signed char)(int)rintf(f.w);
  *(int*)(wq + i) = *(const int*)c;
}

// ---------------- per-token quant of x (both gate & up smoothing) ----------------
__global__ __launch_bounds__(256) void quant_x_kernel(
    const float* __restrict__ x, const float* __restrict__ invg,
    const float* __restrict__ invu, signed char* __restrict__ qg,
    signed char* __restrict__ qu, float* __restrict__ sg,
    float* __restrict__ su, int H) {
  const int t = blockIdx.x, tid = threadIdx.x;
  const float* xr = x + (size_t)t * H;
  const int c0 = tid * 16;  // 256 threads * 16 = 4096 = H
  float xg[16], xu[16];
  float mg = 0.f, mu = 0.f;
#pragma unroll
  for (int v = 0; v < 4; ++v) {
    float4 f = *(const float4*)(xr + c0 + v * 4);
    float4 ig = *(const float4*)(invg + c0 + v * 4);
    float4 iu = *(const float4*)(invu + c0 + v * 4);
    float b0 = bf16_rne_f(f.x), b1 = bf16_rne_f(f.y);
    float b2 = bf16_rne_f(f.z), b3 = bf16_rne_f(f.w);
    xg[v * 4 + 0] = b0 * ig.x; xg[v * 4 + 1] = b1 * ig.y;
    xg[v * 4 + 2] = b2 * ig.z; xg[v * 4 + 3] = b3 * ig.w;
    xu[v * 4 + 0] = b0 * iu.x; xu[v * 4 + 1] = b1 * iu.y;
    xu[v * 4 + 2] = b2 * iu.z; xu[v * 4 + 3] = b3 * iu.w;
#pragma unroll
    for (int j = 0; j < 4; ++j) {
      mg = fmaxf(mg, fabsf(xg[v * 4 + j]));
      mu = fmaxf(mu, fabsf(xu[v * 4 + j]));
    }
  }
#pragma unroll
  for (int off = 32; off > 0; off >>= 1) {
    mg = fmaxf(mg, __shfl_xor(mg, off));
    mu = fmaxf(mu, __shfl_xor(mu, off));
  }
  __shared__ float smg[4], smu[4];
  if ((tid & 63) == 0) { smg[tid >> 6] = mg; smu[tid >> 6] = mu; }
  __syncthreads();
  mg = fmaxf(fmaxf(smg[0], smg[1]), fmaxf(smg[2], smg[3]));
  mu = fmaxf(fmaxf(smu[0], smu[1]), fmaxf(smu[2], smu[3]));
  const float scg = fmaxf(mg / 127.0f, 1e-8f);  // true division, matches np
  const float scu = fmaxf(mu / 127.0f, 1e-8f);
  signed char og[16] __attribute__((aligned(16)));
  signed char ou[16] __attribute__((aligned(16)));
#pragma unroll
  for (int j = 0; j < 16; ++j) {
    og[j] = (signed char)(int)fminf(fmaxf(rintf(xg[j] / scg), -127.f), 127.f);
    ou[j] = (signed char)(int)fminf(fmaxf(rintf(xu[j] / scu), -127.f), 127.f);
  }
  *(i32x4*)(qg + (size_t)t * H + c0) = *(const i32x4*)og;
  *(i32x4*)(qu + (size_t)t * H + c0) = *(const i32x4*)ou;
  if (tid == 0) { sg[t] = scg; su[t] = scu; }
}

// ---------------- fused gate+up GEMM + SwiGLU -> inter (bf16 bits) ----------------
// Tile 256(M) x 128(N), BK=64, 512 threads, 8 waves as 4Mx2N (64x64/wave).
// 3 LDS buffers (48KB each = 144KB), prefetch lead 2 K-tiles, vmcnt(6)
// steady state. Per K-tile: phase G (16 MFMA) + phase U (16 MFMA), each
// barrier-sandwiched. Stage issues go to buffer (kt+2)%3, reads from kt%3.
#define G1_STAGE_G(b, kt)                                                     \
  {                                                                           \
    _Pragma("unroll") for (int p = 0; p < 2; ++p) {                           \
      const int g_ = p * 512 + tid;                                           \
      const int r_ = g_ >> 2;                                                 \
      const int c_ = (g_ & 3) ^ ((r_ >> 1) & 3);                              \
      async16(&Ag[b][g_ * 16],                                                \
              qg + rowbase_a + (size_t)r_ * H + ((kt) << 6) + c_ * 16);       \
    }                                                                         \
    {                                                                         \
      const int r_ = tid >> 2;                                                \
      const int c_ = (tid & 3) ^ ((r_ >> 1) & 3);                             \
      async16(&Bg[b][tid * 16],                                               \
              wg + rowbase_b + (size_t)r_ * H + ((kt) << 6) + c_ * 16);       \
    }                                                                         \
  }

#define G1_STAGE_U(b, kt)                                                     \
  {                                                                           \
    _Pragma("unroll") for (int p = 0; p < 2; ++p) {                           \
      const int g_ = p * 512 + tid;                                           \
      const int r_ = g_ >> 2;                                                 \
      const int c_ = (g_ & 3) ^ ((r_ >> 1) & 3);                              \
      async16(&Au[b][g_ * 16],                                                \
              qu + rowbase_a + (size_t)r_ * H + ((kt) << 6) + c_ * 16);       \
    }                                                                         \
    {                                                                         \
      const int r_ = tid >> 2;                                                \
      const int c_ = (tid & 3) ^ ((r_ >> 1) & 3);                             \
      async16(&Bu[b][tid * 16],                                               \
              wu + rowbase_b + (size_t)r_ * H + ((kt) << 6) + c_ * 16);       \
    }                                                                         \
  }

__global__ __launch_bounds__(512, 2) void gemm1_kernel(
    const signed char* __restrict__ qg, const signed char* __restrict__ qu,
    const float* __restrict__ sg, const float* __restrict__ su,
    const signed char* __restrict__ wg, const signed char* __restrict__ wu,
    const float* __restrict__ swg, const float* __restrict__ swu,
    unsigned short* __restrict__ inter, int H, int I) {
  __shared__ signed char Ag[3][256 * 64] __attribute__((aligned(16)));
  __shared__ signed char Au[3][256 * 64] __attribute__((aligned(16)));
  __shared__ signed char Bg[3][128 * 64] __attribute__((aligned(16)));
  __shared__ signed char Bu[3][128 * 64] __attribute__((aligned(16)));
  const int tid = threadIdx.x;
  const int lane = tid & 63, wave = tid >> 6;
  const int row0 = blockIdx.x * 256, col0 = blockIdx.y * 128;
  const int wm = wave >> 1, wn = wave & 1;  // 4x2 wave grid
  const int mrow = lane & 15, quad = lane >> 4;
  const int NT = H >> 6;
  const size_t rowbase_a = (size_t)row0 * H;
  const size_t rowbase_b = (size_t)col0 * H;

  // loop-invariant swizzled LDS read offsets
  int offA[4], offB[4];
#pragma unroll
  for (int i = 0; i < 4; ++i) {
    const int ra = wm * 64 + i * 16 + mrow;
    offA[i] = ra * 64 + ((quad ^ ((ra >> 1) & 3)) << 4);
    const int rb = wn * 64 + i * 16 + mrow;
    offB[i] = rb * 64 + ((quad ^ ((rb >> 1) & 3)) << 4);
  }

  i32x4 accG[4][4], accU[4][4];
#pragma unroll
  for (int i = 0; i < 4; ++i)
#pragma unroll
    for (int j = 0; j < 4; ++j) {
      accG[i][j] = i32x4{0, 0, 0, 0};
      accU[i][j] = i32x4{0, 0, 0, 0};
    }

  // prologue: tiles 0 and 1 fully issued; wait for tile 0 (keep 6 in flight)
  G1_STAGE_G(0, 0);
  G1_STAGE_U(0, 0);
  G1_STAGE_G(1, 1);
  G1_STAGE_U(1, 1);
  WAIT_VM6;
  BARRIER;

  int bc = 0;
  for (int kt = 0; kt < NT; ++kt) {
    const int bs = (bc >= 1) ? bc - 1 : 2;  // (kt+2)%3

    // ---- phase G: stage-issue + ds_read, then barrier-sandwiched MFMA ----
    if (kt + 2 < NT) G1_STAGE_G(bs, kt + 2);
    i32x4 aG[4], bG[4];
#pragma unroll
    for (int i = 0; i < 4; ++i) {
      aG[i] = *(const i32x4*)(&Ag[bc][0] + offA[i]);
      bG[i] = *(const i32x4*)(&Bg[bc][0] + offB[i]);
    }
    BARRIER;
    LGKM0;
    __builtin_amdgcn_s_setprio(1);
#pragma unroll
    for (int i = 0; i < 4; ++i)
#pragma unroll
      for (int j = 0; j < 4; ++j) accG[i][j] = mfma_i8(aG[i], bG[j], accG[i][j]);
    __builtin_amdgcn_s_setprio(0);
    BARRIER;

    // ---- phase U ----
    if (kt + 2 < NT) G1_STAGE_U(bs, kt + 2);
    i32x4 aU[4], bU[4];
#pragma unroll
    for (int i = 0; i < 4; ++i) {
      aU[i] = *(const i32x4*)(&Au[bc][0] + offA[i]);
      bU[i] = *(const i32x4*)(&Bu[bc][0] + offB[i]);
    }
    BARRIER;
    LGKM0;
    __builtin_amdgcn_s_setprio(1);
#pragma unroll
    for (int i = 0; i < 4; ++i)
#pragma unroll
      for (int j = 0; j < 4; ++j) accU[i][j] = mfma_i8(aU[i], bU[j], accU[i][j]);
    __builtin_amdgcn_s_setprio(0);

    // end-of-tile: gate tile kt+1 (tile kt+2's 6 loads stay in flight)
    if (kt + 2 < NT) {
      WAIT_VM6;
      BARRIER;
    } else if (kt + 1 < NT) {
      WAIT_VM0;
      BARRIER;
    }
    bc = (bc >= 2) ? 0 : bc + 1;
  }

  // epilogue: dequant, silu(g)*u, clip +-10, bf16 RNE, store
  float swgc[4], swuc[4];
#pragma unroll
  for (int j = 0; j < 4; ++j) {
    const int c = col0 + wn * 64 + j * 16 + mrow;
    swgc[j] = swg[c];
    swuc[j] = swu[c];
  }
#pragma unroll
  for (int i = 0; i < 4; ++i) {
#pragma unroll
    for (int r = 0; r < 4; ++r) {
      const int row = row0 + wm * 64 + i * 16 + quad * 4 + r;
      const float sgr = sg[row], sur = su[row];
#pragma unroll
      for (int j = 0; j < 4; ++j) {
        const int c = col0 + wn * 64 + j * 16 + mrow;
        const float g = (float)accG[i][j][r] * sgr * swgc[j];
        const float u = (float)accU[i][j][r] * sur * swuc[j];
        const float sig = 1.f / (1.f + expf(-g));
        float v = (g * sig) * u;
        v = fminf(fmaxf(v, -10.f), 10.f);
        inter[(size_t)row * I + c] = bf16_bits(v);
      }
    }
  }
}

// ---------------- per-token quant of inter ----------------
__global__ __launch_bounds__(256) void quant_i_kernel(
    const unsigned short* __restrict__ inter, const float* __restrict__ invi,
    signed char* __restrict__ qi, float* __restrict__ si, int I) {
  const int t = blockIdx.x, tid = threadIdx.x;
  const unsigned short* ir = inter + (size_t)t * I;
  const int c0 = tid * 8;  // 256*8 = 2048 = I
  uint4 pk = *(const uint4*)(ir + c0);
  float4 i0 = *(const float4*)(invi + c0);
  float4 i1 = *(const float4*)(invi + c0 + 4);
  float xs[8];
  xs[0] = bf16_to_f(pk.x & 0xffffu) * i0.x;
  xs[1] = bf16_to_f(pk.x >> 16) * i0.y;
  xs[2] = bf16_to_f(pk.y & 0xffffu) * i0.z;
  xs[3] = bf16_to_f(pk.y >> 16) * i0.w;
  xs[4] = bf16_to_f(pk.z & 0xffffu) * i1.x;
  xs[5] = bf16_to_f(pk.z >> 16) * i1.y;
  xs[6] = bf16_to_f(pk.w & 0xffffu) * i1.z;
  xs[7] = bf16_to_f(pk.w >> 16) * i1.w;
  float m = 0.f;
#pragma unroll
  for (int j = 0; j < 8; ++j) m = fmaxf(m, fabsf(xs[j]));
#pragma unroll
  for (int off = 32; off > 0; off >>= 1) m = fmaxf(m, __shfl_xor(m, off));
  __shared__ float sm[4];
  if ((tid & 63) == 0) sm[tid >> 6] = m;
  __syncthreads();
  m = fmaxf(fmaxf(sm[0], sm[1]), fmaxf(sm[2], sm[3]));
  const float s = fmaxf(m / 127.0f, 1e-8f);
  signed char o[8] __attribute__((aligned(8)));
#pragma unroll
  for (int j = 0; j < 8; ++j)
    o[j] = (signed char)(int)fminf(fmaxf(rintf(xs[j] / s), -127.f), 127.f);
  *(unsigned long long*)(qi + (size_t)t * I + c0) = *(const unsigned long long*)o;
  if (tid == 0) si[t] = s;
}

// ---------------- down GEMM -> out fp32 ----------------
// Tile 256(M) x 256(N), BK=64, 512 threads, 8 waves as 2Mx4N (128x64/wave).
// 4 LDS buffers (32KB each = 128KB), prefetch lead 3 K-tiles, vmcnt(8)
// steady state. Per K-tile: 2 phases x 16 MFMA (M-half split; B-frags
// register-resident across both phases).
#define G2_STAGE_A(b, kt)                                                     \
  {                                                                           \
    _Pragma("unroll") for (int p = 0; p < 2; ++p) {                           \
      const int g_ = p * 512 + tid;                                           \
      const int r_ = g_ >> 2;                                                 \
      const int c_ = (g_ & 3) ^ ((r_ >> 1) & 3);                              \
      async16(&As[b][g_ * 16],                                                \
              qi + rowbase_a + (size_t)r_ * I + ((kt) << 6) + c_ * 16);       \
    }                                                                         \
  }

#define G2_STAGE_B(b, kt)                                                     \
  {                                                                           \
    _Pragma("unroll") for (int p = 0; p < 2; ++p) {                           \
      const int g_ = p * 512 + tid;                                           \
      const int r_ = g_ >> 2;                                                 \
      const int c_ = (g_ & 3) ^ ((r_ >> 1) & 3);                              \
      async16(&Bs[b][g_ * 16],                                                \
              wd + rowbase_b + (size_t)r_ * I + ((kt) << 6) + c_ * 16);       \
    }                                                                         \
  }

__global__ __launch_bounds__(512, 2) void gemm2_kernel(
    const signed char* __restrict__ qi, const float* __restrict__ si,
    const signed char* __restrict__ wd, const float* __restrict__ swd,
    float* __restrict__ out, int H, int I) {
  __shared__ signed char As[4][256 * 64] __attribute__((aligned(16)));
  __shared__ signed char Bs[4][256 * 64] __attribute__((aligned(16)));
  const int tid = threadIdx.x;
  const int lane = tid & 63, wave = tid >> 6;
  const int row0 = blockIdx.x * 256, col0 = blockIdx.y * 256;
  const int wm = wave >> 2, wn = wave & 3;  // 2x4 wave grid
  const int mrow = lane & 15, quad = lane >> 4;
  const int NT = I >> 6;
  const size_t rowbase_a = (size_t)row0 * I;
  const size_t rowbase_b = (size_t)col0 * I;

  int offA[8], offB[4];
#pragma unroll
  for (int i = 0; i < 8; ++i) {
    const int ra = wm * 128 + i * 16 + mrow;
    offA[i] = ra * 64 + ((quad ^ ((ra >> 1) & 3)) << 4);
  }
#pragma unroll
  for (int j = 0; j < 4; ++j) {
    const int rb = wn * 64 + j * 16 + mrow;
    offB[j] = rb * 64 + ((quad ^ ((rb >> 1) & 3)) << 4);
  }

  i32x4 acc[8][4];
#pragma unroll
  for (int i = 0; i < 8; ++i)
#pragma unroll
    for (int j = 0; j < 4; ++j) acc[i][j] = i32x4{0, 0, 0, 0};

  // prologue: tiles 0,1,2 fully issued; wait for tile 0 (keep 8 in flight)
  G2_STAGE_A(0, 0);
  G2_STAGE_B(0, 0);
  G2_STAGE_A(1, 1);
  G2_STAGE_B(1, 1);
  G2_STAGE_A(2, 2);
  G2_STAGE_B(2, 2);
  WAIT_VM8;
  BARRIER;

  int bc = 0;
  for (int kt = 0; kt < NT; ++kt) {
    const int bs = (kt + 3) & 3;

    // ---- phase 0: M-frags 0..3 x all B ----
    if (kt + 3 < NT) G2_STAGE_A(bs, kt + 3);
    i32x4 a[4], b[4];
#pragma unroll
    for (int j = 0; j < 4; ++j) b[j] = *(const i32x4*)(&Bs[bc][0] + offB[j]);
#pragma unroll
    for (int i = 0; i < 4; ++i) a[i] = *(const i32x4*)(&As[bc][0] + offA[i]);
    BARRIER;
    LGKM0;
    __builtin_amdgcn_s_setprio(1);
#pragma unroll
    for (int i = 0; i < 4; ++i)
#pragma unroll
      for (int j = 0; j < 4; ++j) acc[i][j] = mfma_i8(a[i], b[j], acc[i][j]);
    __builtin_amdgcn_s_setprio(0);
    BARRIER;

    // ---- phase 1: M-frags 4..7 x all B (B still in regs) ----
    if (kt + 3 < NT) G2_STAGE_B(bs, kt + 3);
    i32x4 a2[4];
#pragma unroll
    for (int i = 0; i < 4; ++i)
      a2[i] = *(const i32x4*)(&As[bc][0] + offA[4 + i]);
    BARRIER;
    LGKM0;
    __builtin_amdgcn_s_setprio(1);
#pragma unroll
    for (int i = 0; i < 4; ++i)
#pragma unroll
      for (int j = 0; j < 4; ++j)
        acc[4 + i][j] = mfma_i8(a2[i], b[j], acc[4 + i][j]);
    __builtin_amdgcn_s_setprio(0);

    // end-of-tile: gate tile kt+1 (tiles kt+2, kt+3 stay in flight)
    if (kt + 3 < NT) {
      WAIT_VM8;
      BARRIER;
    } else if (kt + 2 < NT) {
      WAIT_VM4;
      BARRIER;
    } else if (kt + 1 < NT) {
      WAIT_VM0;
      BARRIER;
    }
    bc = (bc + 1) & 3;
  }

  float swc[4];
#pragma unroll
  for (int j = 0; j < 4; ++j) swc[j] = swd[col0 + wn * 64 + j * 16 + mrow];
#pragma unroll
  for (int i = 0; i < 8; ++i) {
#pragma unroll
    for (int r = 0; r < 4; ++r) {
      const int row = row0 + wm * 128 + i * 16 + quad * 4 + r;
      const float sir = si[row];
#pragma unroll
      for (int j = 0; j < 4; ++j) {
        const int c = col0 + wn * 64 + j * 16 + mrow;
        out[(size_t)row * H + c] = (float)acc[i][j][r] * sir * swc[j];
      }
    }
  }
}

extern "C" void kernel_launch(void* const* d_in, const int* in_sizes, int n_in,
                              void* d_out, int out_size, void* d_ws,
                              size_t ws_size, hipStream_t stream) {
  const float* x = (const float*)d_in[0];
  const float* w_gate = (const float*)d_in[1];
  const float* s_wgate = (const float*)d_in[2];
  const float* w_up = (const float*)d_in[3];
  const float* s_wup = (const float*)d_in[4];
  const float* w_down = (const float*)d_in[5];
  const float* s_wdown = (const float*)d_in[6];
  const float* inv_gate = (const float*)d_in[7];
  const float* inv_up = (const float*)d_in[8];
  const float* inv_inter = (const float*)d_in[9];
  float* out = (float*)d_out;

  const int H = in_sizes[6];          // 4096
  const int I = in_sizes[2];          // 2048
  const int T = in_sizes[0] / H;      // 8192

  char* ws = (char*)d_ws;
  size_t off = 0;
  signed char* wqg = (signed char*)(ws + off); off += (size_t)I * H;
  signed char* wqu = (signed char*)(ws + off); off += (size_t)I * H;
  signed char* wqd = (signed char*)(ws + off); off += (size_t)H * I;
  signed char* qg  = (signed char*)(ws + off); off += (size_t)T * H;
  signed char* qu  = (signed char*)(ws + off); off += (size_t)T * H;
  unsigned short* inter = (unsigned short*)(ws + off); off += (size_t)T * I * 2;
  float* sg = (float*)(ws + off); off += (size_t)T * 4;
  float* su = (float*)(ws + off); off += (size_t)T * 4;
  float* si = (float*)(ws + off); off += (size_t)T * 4;
  signed char* qi = qg;  // qg is dead after gemm1; reuse for qi

  const int nW = I * H;
  wconv_kernel<<<nW / 1024, 256, 0, stream>>>(w_gate, wqg, nW);
  wconv_kernel<<<nW / 1024, 256, 0, stream>>>(w_up, wqu, nW);
  wconv_kernel<<<nW / 1024, 256, 0, stream>>>(w_down, wqd, nW);

  quant_x_kernel<<<T, 256, 0, stream>>>(x, inv_gate, inv_up, qg, qu, sg, su, H);

  dim3 g1(T / 256, I / 128);
  gemm1_kernel<<<g1, 512, 0, stream>>>(qg, qu, sg, su, wqg, wqu, s_wgate,
                                       s_wup, inter, H, I);

  quant_i_kernel<<<T, 256, 0, stream>>>(inter, inv_inter, qi, si, I);

  dim3 g2(T / 256, H / 256);
  gemm2_kernel<<<g2, 512, 0, stream>>>(qi, si, wqd, s_wdown, out, H, I);
}

// Round 3
// 612.139 us; speedup vs baseline: 1.0946x; 1.0946x over previous
//
#include <hip/hip_runtime.h>
#include <hip/hip_bf16.h>

// DeepseekV4 shared expert: int8 dynamic-quant SwiGLU MLP.
// T=8192, H=4096, I=2048.
// Pipeline: wconv x3 -> quant_x -> gemm1(gate+up fused, silu, clip, bf16)
//           -> quant_inter -> gemm2 -> out fp32.
//
// GEMMs: round-0 structure (128x128 tile, 256 threads, 4 waves, 2 blocks/CU)
// + double-buffered counted-vmcnt staging (issue tile k+1 at top of iter k,
// wait vmcnt(8/4) = tile k's loads; never drain to 0 in steady state)
// + XOR bank-swizzle on the global source / ds_read address (linear LDS dest).

typedef __attribute__((ext_vector_type(4))) int i32x4;

__device__ __forceinline__ void async16(void* lds, const void* g) {
  __builtin_amdgcn_global_load_lds(
      (const __attribute__((address_space(1))) void*)g,
      (__attribute__((address_space(3))) void*)lds, 16, 0, 0);
}

__device__ __forceinline__ i32x4 mfma_i8(i32x4 a, i32x4 b, i32x4 c) {
  return __builtin_amdgcn_mfma_i32_16x16x64_i8(a, b, c, 0, 0, 0);
}

// fp32 -> bf16 round-to-nearest-even, back to fp32
__device__ __forceinline__ float bf16_rne_f(float f) {
  unsigned u = __float_as_uint(f);
  u += 0x7fffu + ((u >> 16) & 1u);
  return __uint_as_float(u & 0xffff0000u);
}

__device__ __forceinline__ unsigned short bf16_bits(float f) {
  unsigned u = __float_as_uint(f);
  u += 0x7fffu + ((u >> 16) & 1u);
  return (unsigned short)(u >> 16);
}

__device__ __forceinline__ float bf16_to_f(unsigned short h) {
  return __uint_as_float(((unsigned)h) << 16);
}

#define BARRIER __builtin_amdgcn_s_barrier()
#define LGKM0 asm volatile("s_waitcnt lgkmcnt(0)" ::: "memory")
#define WAIT_VM8 asm volatile("s_waitcnt vmcnt(8)" ::: "memory")
#define WAIT_VM4 asm volatile("s_waitcnt vmcnt(4)" ::: "memory")
#define WAIT_VM0 asm volatile("s_waitcnt vmcnt(0)" ::: "memory")

// ---------------- weight fp32 (int8-valued) -> int8 ----------------
__global__ void wconv_kernel(const float* __restrict__ w,
                             signed char* __restrict__ wq, int n) {
  int i = (blockIdx.x * 256 + threadIdx.x) * 4;
  if (i >= n) return;
  float4 f = *(const float4*)(w + i);
  signed char c[4] __attribute__((aligned(4)));
  c[0] = (signed char)(int)rintf(f.x);
  c[1] = (signed char)(int)rintf(f.y);
  c[2] = (signed char)(int)rintf(f.z);
  c[3] = (signed char)(int)rintf(f.w);
  *(int*)(wq + i) = *(const int*)c;
}

// ---------------- per-token quant of x (both gate & up smoothing) ----------------
__global__ __launch_bounds__(256) void quant_x_kernel(
    const float* __restrict__ x, const float* __restrict__ invg,
    const float* __restrict__ invu, signed char* __restrict__ qg,
    signed char* __restrict__ qu, float* __restrict__ sg,
    float* __restrict__ su, int H) {
  const int t = blockIdx.x, tid = threadIdx.x;
  const float* xr = x + (size_t)t * H;
  const int c0 = tid * 16;  // 256 threads * 16 = 4096 = H
  float xg[16], xu[16];
  float mg = 0.f, mu = 0.f;
#pragma unroll
  for (int v = 0; v < 4; ++v) {
    float4 f = *(const float4*)(xr + c0 + v * 4);
    float4 ig = *(const float4*)(invg + c0 + v * 4);
    float4 iu = *(const float4*)(invu + c0 + v * 4);
    float b0 = bf16_rne_f(f.x), b1 = bf16_rne_f(f.y);
    float b2 = bf16_rne_f(f.z), b3 = bf16_rne_f(f.w);
    xg[v * 4 + 0] = b0 * ig.x; xg[v * 4 + 1] = b1 * ig.y;
    xg[v * 4 + 2] = b2 * ig.z; xg[v * 4 + 3] = b3 * ig.w;
    xu[v * 4 + 0] = b0 * iu.x; xu[v * 4 + 1] = b1 * iu.y;
    xu[v * 4 + 2] = b2 * iu.z; xu[v * 4 + 3] = b3 * iu.w;
#pragma unroll
    for (int j = 0; j < 4; ++j) {
      mg = fmaxf(mg, fabsf(xg[v * 4 + j]));
      mu = fmaxf(mu, fabsf(xu[v * 4 + j]));
    }
  }
#pragma unroll
  for (int off = 32; off > 0; off >>= 1) {
    mg = fmaxf(mg, __shfl_xor(mg, off));
    mu = fmaxf(mu, __shfl_xor(mu, off));
  }
  __shared__ float smg[4], smu[4];
  if ((tid & 63) == 0) { smg[tid >> 6] = mg; smu[tid >> 6] = mu; }
  __syncthreads();
  mg = fmaxf(fmaxf(smg[0], smg[1]), fmaxf(smg[2], smg[3]));
  mu = fmaxf(fmaxf(smu[0], smu[1]), fmaxf(smu[2], smu[3]));
  const float scg = fmaxf(mg / 127.0f, 1e-8f);  // true division, matches np
  const float scu = fmaxf(mu / 127.0f, 1e-8f);
  signed char og[16] __attribute__((aligned(16)));
  signed char ou[16] __attribute__((aligned(16)));
#pragma unroll
  for (int j = 0; j < 16; ++j) {
    og[j] = (signed char)(int)fminf(fmaxf(rintf(xg[j] / scg), -127.f), 127.f);
    ou[j] = (signed char)(int)fminf(fmaxf(rintf(xu[j] / scu), -127.f), 127.f);
  }
  *(i32x4*)(qg + (size_t)t * H + c0) = *(const i32x4*)og;
  *(i32x4*)(qu + (size_t)t * H + c0) = *(const i32x4*)ou;
  if (tid == 0) { sg[t] = scg; su[t] = scu; }
}

// ---------------- fused gate+up GEMM + SwiGLU -> inter (bf16 bits) ----------------
// 128x128 tile, 256 threads (4 waves, 2x2), BK=64, double-buffered LDS (64KB),
// counted vmcnt(8): tile k+1's 8 loads issued at top of iter k, waited at top
// of iter k+1. XOR swizzle on source chunk + ds_read chunk.
#define G1_STAGE(b, kk)                                                       \
  {                                                                           \
    _Pragma("unroll") for (int p = 0; p < 2; ++p) {                           \
      const int g_ = p * 256 + tid;                                           \
      const int r_ = g_ >> 2;                                                 \
      const int c_ = (g_ & 3) ^ ((r_ >> 1) & 3);                              \
      const size_t ga_ = (size_t)(row0 + r_) * H + (kk) + c_ * 16;            \
      const size_t gb_ = (size_t)(col0 + r_) * H + (kk) + c_ * 16;            \
      async16(&Ag[b][g_ * 16], qg + ga_);                                     \
      async16(&Au[b][g_ * 16], qu + ga_);                                     \
      async16(&Bg[b][g_ * 16], wg + gb_);                                     \
      async16(&Bu[b][g_ * 16], wu + gb_);                                     \
    }                                                                         \
  }

__global__ __launch_bounds__(256, 2) void gemm1_kernel(
    const signed char* __restrict__ qg, const signed char* __restrict__ qu,
    const float* __restrict__ sg, const float* __restrict__ su,
    const signed char* __restrict__ wg, const signed char* __restrict__ wu,
    const float* __restrict__ swg, const float* __restrict__ swu,
    unsigned short* __restrict__ inter, int H, int I) {
  __shared__ signed char Ag[2][128 * 64] __attribute__((aligned(16)));
  __shared__ signed char Au[2][128 * 64] __attribute__((aligned(16)));
  __shared__ signed char Bg[2][128 * 64] __attribute__((aligned(16)));
  __shared__ signed char Bu[2][128 * 64] __attribute__((aligned(16)));
  const int tid = threadIdx.x;
  const int lane = tid & 63, wave = tid >> 6;
  const int row0 = blockIdx.x * 128, col0 = blockIdx.y * 128;
  const int wm = (wave & 1) * 64, wn = (wave >> 1) * 64;
  const int mrow = lane & 15, quad = lane >> 4;
  const int NT = H >> 6;

  // loop-invariant swizzled LDS read offsets
  int offA[4], offB[4];
#pragma unroll
  for (int i = 0; i < 4; ++i) {
    const int ra = wm + i * 16 + mrow;
    offA[i] = ra * 64 + ((quad ^ ((ra >> 1) & 3)) << 4);
    const int rb = wn + i * 16 + mrow;
    offB[i] = rb * 64 + ((quad ^ ((rb >> 1) & 3)) << 4);
  }

  i32x4 accG[4][4], accU[4][4];
#pragma unroll
  for (int i = 0; i < 4; ++i)
#pragma unroll
    for (int j = 0; j < 4; ++j) {
      accG[i][j] = i32x4{0, 0, 0, 0};
      accU[i][j] = i32x4{0, 0, 0, 0};
    }

  G1_STAGE(0, 0);  // prologue: tile 0 in flight (8 loads/thread)

  int cur = 0;
  for (int kt = 0; kt < NT; ++kt) {
    if (kt + 1 < NT) {
      G1_STAGE(cur ^ 1, (kt + 1) << 6);  // outstanding: 16
      WAIT_VM8;                          // tile kt's 8 landed; kt+1 in flight
    } else {
      WAIT_VM0;
    }
    BARRIER;  // all waves' tile-kt loads are in LDS

    i32x4 aG[4], aU[4], bG[4], bU[4];
#pragma unroll
    for (int i = 0; i < 4; ++i) {
      aG[i] = *(const i32x4*)(&Ag[cur][0] + offA[i]);
      aU[i] = *(const i32x4*)(&Au[cur][0] + offA[i]);
      bG[i] = *(const i32x4*)(&Bg[cur][0] + offB[i]);
      bU[i] = *(const i32x4*)(&Bu[cur][0] + offB[i]);
    }
#pragma unroll
    for (int i = 0; i < 4; ++i)
#pragma unroll
      for (int j = 0; j < 4; ++j) {
        accG[i][j] = mfma_i8(aG[i], bG[j], accG[i][j]);
        accU[i][j] = mfma_i8(aU[i], bU[j], accU[i][j]);
      }

    LGKM0;    // pin ds_reads above the closing barrier (reads complete)
    BARRIER;  // all waves done reading buf[cur]; safe to overwrite next iter
    cur ^= 1;
  }

  // epilogue: dequant, silu(g)*u, clip +-10, bf16 RNE, store
  float swgc[4], swuc[4];
#pragma unroll
  for (int j = 0; j < 4; ++j) {
    const int c = col0 + wn + j * 16 + mrow;
    swgc[j] = swg[c];
    swuc[j] = swu[c];
  }
#pragma unroll
  for (int i = 0; i < 4; ++i) {
#pragma unroll
    for (int r = 0; r < 4; ++r) {
      const int row = row0 + wm + i * 16 + quad * 4 + r;
      const float sgr = sg[row], sur = su[row];
#pragma unroll
      for (int j = 0; j < 4; ++j) {
        const int c = col0 + wn + j * 16 + mrow;
        const float g = (float)accG[i][j][r] * sgr * swgc[j];
        const float u = (float)accU[i][j][r] * sur * swuc[j];
        const float sig = 1.f / (1.f + expf(-g));
        float v = (g * sig) * u;
        v = fminf(fmaxf(v, -10.f), 10.f);
        inter[(size_t)row * I + c] = bf16_bits(v);
      }
    }
  }
}

// ---------------- per-token quant of inter ----------------
__global__ __launch_bounds__(256) void quant_i_kernel(
    const unsigned short* __restrict__ inter, const float* __restrict__ invi,
    signed char* __restrict__ qi, float* __restrict__ si, int I) {
  const int t = blockIdx.x, tid = threadIdx.x;
  const unsigned short* ir = inter + (size_t)t * I;
  const int c0 = tid * 8;  // 256*8 = 2048 = I
  uint4 pk = *(const uint4*)(ir + c0);
  float4 i0 = *(const float4*)(invi + c0);
  float4 i1 = *(const float4*)(invi + c0 + 4);
  float xs[8];
  xs[0] = bf16_to_f(pk.x & 0xffffu) * i0.x;
  xs[1] = bf16_to_f(pk.x >> 16) * i0.y;
  xs[2] = bf16_to_f(pk.y & 0xffffu) * i0.z;
  xs[3] = bf16_to_f(pk.y >> 16) * i0.w;
  xs[4] = bf16_to_f(pk.z & 0xffffu) * i1.x;
  xs[5] = bf16_to_f(pk.z >> 16) * i1.y;
  xs[6] = bf16_to_f(pk.w & 0xffffu) * i1.z;
  xs[7] = bf16_to_f(pk.w >> 16) * i1.w;
  float m = 0.f;
#pragma unroll
  for (int j = 0; j < 8; ++j) m = fmaxf(m, fabsf(xs[j]));
#pragma unroll
  for (int off = 32; off > 0; off >>= 1) m = fmaxf(m, __shfl_xor(m, off));
  __shared__ float sm[4];
  if ((tid & 63) == 0) sm[tid >> 6] = m;
  __syncthreads();
  m = fmaxf(fmaxf(sm[0], sm[1]), fmaxf(sm[2], sm[3]));
  const float s = fmaxf(m / 127.0f, 1e-8f);
  signed char o[8] __attribute__((aligned(8)));
#pragma unroll
  for (int j = 0; j < 8; ++j)
    o[j] = (signed char)(int)fminf(fmaxf(rintf(xs[j] / s), -127.f), 127.f);
  *(unsigned long long*)(qi + (size_t)t * I + c0) = *(const unsigned long long*)o;
  if (tid == 0) si[t] = s;
}

// ---------------- down GEMM -> out fp32 ----------------
// 128x128 tile, 256 threads, BK=64, double-buffered LDS (32KB), vmcnt(4).
#define G2_STAGE(b, kk)                                                       \
  {                                                                           \
    _Pragma("unroll") for (int p = 0; p < 2; ++p) {                           \
      const int g_ = p * 256 + tid;                                           \
      const int r_ = g_ >> 2;                                                 \
      const int c_ = (g_ & 3) ^ ((r_ >> 1) & 3);                              \
      async16(&As[b][g_ * 16],                                                \
              qi + (size_t)(row0 + r_) * I + (kk) + c_ * 16);                 \
      async16(&Bs[b][g_ * 16],                                                \
              wd + (size_t)(col0 + r_) * I + (kk) + c_ * 16);                 \
    }                                                                         \
  }

__global__ __launch_bounds__(256, 2) void gemm2_kernel(
    const signed char* __restrict__ qi, const float* __restrict__ si,
    const signed char* __restrict__ wd, const float* __restrict__ swd,
    float* __restrict__ out, int H, int I) {
  __shared__ signed char As[2][128 * 64] __attribute__((aligned(16)));
  __shared__ signed char Bs[2][128 * 64] __attribute__((aligned(16)));
  const int tid = threadIdx.x;
  const int lane = tid & 63, wave = tid >> 6;
  const int row0 = blockIdx.x * 128, col0 = blockIdx.y * 128;
  const int wm = (wave & 1) * 64, wn = (wave >> 1) * 64;
  const int mrow = lane & 15, quad = lane >> 4;
  const int NT = I >> 6;

  int offA[4], offB[4];
#pragma unroll
  for (int i = 0; i < 4; ++i) {
    const int ra = wm + i * 16 + mrow;
    offA[i] = ra * 64 + ((quad ^ ((ra >> 1) & 3)) << 4);
    const int rb = wn + i * 16 + mrow;
    offB[i] = rb * 64 + ((quad ^ ((rb >> 1) & 3)) << 4);
  }

  i32x4 acc[4][4];
#pragma unroll
  for (int i = 0; i < 4; ++i)
#pragma unroll
    for (int j = 0; j < 4; ++j) acc[i][j] = i32x4{0, 0, 0, 0};

  G2_STAGE(0, 0);  // prologue: tile 0 in flight (4 loads/thread)

  int cur = 0;
  for (int kt = 0; kt < NT; ++kt) {
    if (kt + 1 < NT) {
      G2_STAGE(cur ^ 1, (kt + 1) << 6);
      WAIT_VM4;
    } else {
      WAIT_VM0;
    }
    BARRIER;

    i32x4 a[4], b[4];
#pragma unroll
    for (int i = 0; i < 4; ++i) {
      a[i] = *(const i32x4*)(&As[cur][0] + offA[i]);
      b[i] = *(const i32x4*)(&Bs[cur][0] + offB[i]);
    }
#pragma unroll
    for (int i = 0; i < 4; ++i)
#pragma unroll
      for (int j = 0; j < 4; ++j) acc[i][j] = mfma_i8(a[i], b[j], acc[i][j]);

    LGKM0;
    BARRIER;
    cur ^= 1;
  }

  float swc[4];
#pragma unroll
  for (int j = 0; j < 4; ++j) swc[j] = swd[col0 + wn + j * 16 + mrow];
#pragma unroll
  for (int i = 0; i < 4; ++i) {
#pragma unroll
    for (int r = 0; r < 4; ++r) {
      const int row = row0 + wm + i * 16 + quad * 4 + r;
      const float sir = si[row];
#pragma unroll
      for (int j = 0; j < 4; ++j) {
        const int c = col0 + wn + j * 16 + mrow;
        out[(size_t)row * H + c] = (float)acc[i][j][r] * sir * swc[j];
      }
    }
  }
}

extern "C" void kernel_launch(void* const* d_in, const int* in_sizes, int n_in,
                              void* d_out, int out_size, void* d_ws,
                              size_t ws_size, hipStream_t stream) {
  const float* x = (const float*)d_in[0];
  const float* w_gate = (const float*)d_in[1];
  const float* s_wgate = (const float*)d_in[2];
  const float* w_up = (const float*)d_in[3];
  const float* s_wup = (const float*)d_in[4];
  const float* w_down = (const float*)d_in[5];
  const float* s_wdown = (const float*)d_in[6];
  const float* inv_gate = (const float*)d_in[7];
  const float* inv_up = (const float*)d_in[8];
  const float* inv_inter = (const float*)d_in[9];
  float* out = (float*)d_out;

  const int H = in_sizes[6];          // 4096
  const int I = in_sizes[2];          // 2048
  const int T = in_sizes[0] / H;      // 8192

  char* ws = (char*)d_ws;
  size_t off = 0;
  signed char* wqg = (signed char*)(ws + off); off += (size_t)I * H;
  signed char* wqu = (signed char*)(ws + off); off += (size_t)I * H;
  signed char* wqd = (signed char*)(ws + off); off += (size_t)H * I;
  signed char* qg  = (signed char*)(ws + off); off += (size_t)T * H;
  signed char* qu  = (signed char*)(ws + off); off += (size_t)T * H;
  unsigned short* inter = (unsigned short*)(ws + off); off += (size_t)T * I * 2;
  float* sg = (float*)(ws + off); off += (size_t)T * 4;
  float* su = (float*)(ws + off); off += (size_t)T * 4;
  float* si = (float*)(ws + off); off += (size_t)T * 4;
  signed char* qi = qg;  // qg is dead after gemm1; reuse for qi

  const int nW = I * H;
  wconv_kernel<<<nW / 1024, 256, 0, stream>>>(w_gate, wqg, nW);
  wconv_kernel<<<nW / 1024, 256, 0, stream>>>(w_up, wqu, nW);
  wconv_kernel<<<nW / 1024, 256, 0, stream>>>(w_down, wqd, nW);

  quant_x_kernel<<<T, 256, 0, stream>>>(x, inv_gate, inv_up, qg, qu, sg, su, H);

  dim3 g1(T / 128, I / 128);
  gemm1_kernel<<<g1, 256, 0, stream>>>(qg, qu, sg, su, wqg, wqu, s_wgate,
                                       s_wup, inter, H, I);

  quant_i_kernel<<<T, 256, 0, stream>>>(inter, inv_inter, qi, si, I);

  dim3 g2(T / 128, H / 128);
  gemm2_kernel<<<g2, 256, 0, stream>>>(qi, si, wqd, s_wdown, out, H, I);
}